// Round 15
// baseline (1030.377 us; speedup 1.0000x reference)
//
#include <hip/hip_runtime.h>

typedef __attribute__((ext_vector_type(8))) short short8;
typedef __attribute__((ext_vector_type(4))) float f32x4;
typedef __attribute__((ext_vector_type(4), aligned(4))) float f32x4u;  // 4B-aligned loads

constexpr int kN = 50000;
constexpr int kE = 300000;
constexpr int kDIN = 963;
constexpr int kH = 256;
constexpr int kNBLK = 6;

__device__ inline unsigned short f2bf(float f) {
    unsigned u = __float_as_uint(f);
    u = u + 0x7FFFu + ((u >> 16) & 1u);   // RTNE
    return (unsigned short)(u >> 16);
}
__device__ inline float bf2f(unsigned short s) {
    return __uint_as_float(((unsigned)s) << 16);
}

__device__ inline void gload_lds16(const void* g, void* l) {
    __builtin_amdgcn_global_load_lds(
        (const __attribute__((address_space(1))) void*)g,
        (__attribute__((address_space(3))) void*)l, 16, 0, 0);
}

// ---------------------------------------------------------------------------
// x fp32 [N][963] -> xbf bf16 [N][1024] zero-padded (RTNE, same as in-kernel)
// ---------------------------------------------------------------------------
__global__ __launch_bounds__(128) void xcvt_kernel(
    const float* __restrict__ x, unsigned short* __restrict__ xbf)
{
    const int row = blockIdx.x;
    const int kb = threadIdx.x * 8;
    const float* xr = x + (long)row * kDIN;
    short8 v;
    if (kb + 8 <= kDIN) {
        f32x4u f0 = *(const f32x4u*)(xr + kb);
        f32x4u f1 = *(const f32x4u*)(xr + kb + 4);
#pragma unroll
        for (int ii = 0; ii < 4; ++ii) {
            v[ii]     = (short)f2bf(f0[ii]);
            v[ii + 4] = (short)f2bf(f1[ii]);
        }
    } else {
#pragma unroll
        for (int ii = 0; ii < 8; ++ii) {
            int k = kb + ii;
            v[ii] = (short)((k < kDIN) ? f2bf(xr[k]) : 0);
        }
    }
    *(short8*)(xbf + (long)row * 1024 + kb) = v;
}

// ---------------------------------------------------------------------------
// Layer-1 dual GEMM from bf16 x (R10-proven structure, pure gload staging):
// [supb | tpreb] = xbf @ [W1|Wl1]^T.  Tile 128 rows x 256 cols, 8 waves
// (2 row x 4 col), grid 782 (2 col-tiles x 391), XCD swizzle.
// LDS = As 16KB + Bs 32KB = 48KB -> 3 blocks/CU.
// ---------------------------------------------------------------------------
__global__ __launch_bounds__(512) void gemm_l1_bf(
    const unsigned short* __restrict__ xbf, const unsigned short* __restrict__ Bt,
    const float* __restrict__ bias,
    unsigned short* __restrict__ supb, unsigned short* __restrict__ tpreb)
{
    __shared__ __align__(16) char smem[49152];
    char* As = smem;             // 128 rows x 128 B
    char* Bs = smem + 16384;     // 256 cols x 128 B

    const int tid = threadIdx.x;
    const int wid = tid >> 6;
    const int lane = tid & 63;
    const int wr = wid >> 2, wc = wid & 3;

    const int nwg = gridDim.x;
    const int q = nwg >> 3, r = nwg & 7;
    const int xcd = blockIdx.x & 7, idx = blockIdx.x >> 3;
    const int t = (xcd < r ? xcd * (q + 1) : r * (q + 1) + (xcd - r) * q) + idx;
    const int r0 = (t >> 1) * 128;
    const int c0 = (t & 1) * 256;

    f32x4 acc[4][4];
#pragma unroll
    for (int i = 0; i < 4; ++i)
#pragma unroll
        for (int j = 0; j < 4; ++j) acc[i][j] = f32x4{0.f, 0.f, 0.f, 0.f};

    const int l_row = lane >> 3;
    const int l_c   = lane & 7;

    for (int k0 = 0; k0 < 1024; k0 += 64) {
#pragma unroll
        for (int p = 0; p < 4; ++p) {
            int row = wid * 32 + p * 8 + l_row;          // 0..255
            int csw = l_c ^ (row & 7);
            const unsigned short* g = Bt + (long)(c0 + row) * 1024 + k0 + csw * 8;
            gload_lds16(g, Bs + (wid * 32 + p * 8) * 128);
        }
#pragma unroll
        for (int p = 0; p < 2; ++p) {
            int row = wid * 16 + p * 8 + l_row;          // 0..127
            int grow = r0 + row; if (grow >= kN) grow = kN - 1;
            int csw = l_c ^ (row & 7);
            const unsigned short* g = xbf + (long)grow * 1024 + k0 + csw * 8;
            gload_lds16(g, As + (wid * 16 + p * 8) * 128);
        }
        __syncthreads();
#pragma unroll
        for (int kk = 0; kk < 2; ++kk) {
            short8 af[4], bfr[4];
            const int kg = kk * 4 + (lane >> 4);
#pragma unroll
            for (int nr = 0; nr < 4; ++nr) {
                int row = wr * 64 + nr * 16 + (lane & 15);
                af[nr] = *(const short8*)(As + row * 128 + ((kg ^ (row & 7)) << 4));
            }
#pragma unroll
            for (int mc = 0; mc < 4; ++mc) {
                int row = wc * 64 + mc * 16 + (lane & 15);
                bfr[mc] = *(const short8*)(Bs + row * 128 + ((kg ^ (row & 7)) << 4));
            }
#pragma unroll
            for (int mc = 0; mc < 4; ++mc)
#pragma unroll
                for (int nr = 0; nr < 4; ++nr)
                    acc[mc][nr] = __builtin_amdgcn_mfma_f32_16x16x32_bf16(
                        bfr[mc], af[nr], acc[mc][nr], 0, 0, 0);
        }
        __syncthreads();
    }

    const bool isSup = (c0 == 0);
    unsigned short* outp = isSup ? supb : tpreb;
    float* eL = (float*)smem;
    const int wrow = wr * 16 + (lane & 15);
    const int qc = (lane >> 4) << 2;

    for (int nr = 0; nr < 4; ++nr) {
        __syncthreads();
#pragma unroll
        for (int mc = 0; mc < 4; ++mc) {
            const int col = wc * 64 + mc * 16 + qc;
            f32x4 v = acc[mc][nr];
            if (!isSup) v += *(const f32x4*)(bias + col);
            const int c16 = col >> 2;
            *(f32x4*)(eL + wrow * 256 + ((c16 ^ wrow) << 2)) = v;
        }
        __syncthreads();
        const int tr = tid >> 4, j = tid & 15;
        const int gr = r0 + (tr >> 4) * 64 + nr * 16 + (tr & 15);
        if (gr < kN) {
#pragma unroll
            for (int p = 0; p < 2; ++p) {
                const int u = j + 16 * p;
                f32x4 lo = *(const f32x4*)(eL + tr * 256 + (((2 * u) ^ tr) << 2));
                f32x4 hi = *(const f32x4*)(eL + tr * 256 + (((2 * u + 1) ^ tr) << 2));
                uint4 pk;
                pk.x = (unsigned)f2bf(lo[0]) | ((unsigned)f2bf(lo[1]) << 16);
                pk.y = (unsigned)f2bf(lo[2]) | ((unsigned)f2bf(lo[3]) << 16);
                pk.z = (unsigned)f2bf(hi[0]) | ((unsigned)f2bf(hi[1]) << 16);
                pk.w = (unsigned)f2bf(hi[2]) | ((unsigned)f2bf(hi[3]) << 16);
                *(uint4*)(outp + (long)gr * 256 + u * 8) = pk;
            }
        }
    }
}

// ---------------------------------------------------------------------------
// Layer-1 dual GEMM, fp32-A fallback (R13 version, used if ws too small)
// ---------------------------------------------------------------------------
__global__ __launch_bounds__(512) void gemm_l1(
    const float* __restrict__ Av, const unsigned short* __restrict__ Bt,
    const float* __restrict__ bias,
    unsigned short* __restrict__ supb, unsigned short* __restrict__ tpreb,
    int M, int Kpad, int Kvalid, int Astride)
{
    __shared__ __align__(16) char smem[81920];
    char* As  = smem;
    char* Bs0 = smem + 16384;
    char* Bs1 = smem + 49152;

    const int tid = threadIdx.x;
    const int wid = tid >> 6;
    const int lane = tid & 63;
    const int wr = wid >> 2, wc = wid & 3;

    const int nwg = gridDim.x;
    const int q = nwg >> 3, r = nwg & 7;
    const int xcd = blockIdx.x & 7, idx = blockIdx.x >> 3;
    const int t = (xcd < r ? xcd * (q + 1) : r * (q + 1) + (xcd - r) * q) + idx;
    const int r0 = t * 128;

    f32x4 acc[2][4][4];
#pragma unroll
    for (int hf = 0; hf < 2; ++hf)
#pragma unroll
        for (int i = 0; i < 4; ++i)
#pragma unroll
            for (int j = 0; j < 4; ++j) acc[hf][i][j] = f32x4{0.f, 0.f, 0.f, 0.f};

    const int l_row = lane >> 3;
    const int l_c   = lane & 7;

    for (int k0 = 0; k0 < Kpad; k0 += 64) {
#pragma unroll
        for (int p = 0; p < 4; ++p) {
            int row = wid * 32 + p * 8 + l_row;
            int csw = l_c ^ (row & 7);
            const unsigned short* g0 = Bt + (long)row * Kpad + k0 + csw * 8;
            gload_lds16(g0, Bs0 + (wid * 32 + p * 8) * 128);
            const unsigned short* g1 = Bt + (long)(256 + row) * Kpad + k0 + csw * 8;
            gload_lds16(g1, Bs1 + (wid * 32 + p * 8) * 128);
        }
        {
            const int row = tid >> 2;
            const int kq = tid & 3;
            int grow = r0 + row; if (grow >= M) grow = M - 1;
            const float* ar = Av + (long)grow * Astride;
#pragma unroll
            for (int j = 0; j < 2; ++j) {
                int k16 = kq * 2 + j;
                int kb = k0 + k16 * 8;
                short8 v;
                if (kb + 8 <= Kvalid) {
                    f32x4u f0 = *(const f32x4u*)(ar + kb);
                    f32x4u f1 = *(const f32x4u*)(ar + kb + 4);
#pragma unroll
                    for (int ii = 0; ii < 4; ++ii) {
                        v[ii]     = (short)f2bf(f0[ii]);
                        v[ii + 4] = (short)f2bf(f1[ii]);
                    }
                } else {
#pragma unroll
                    for (int ii = 0; ii < 8; ++ii) {
                        int k = kb + ii;
                        float f = (k < Kvalid) ? ar[k] : 0.f;
                        v[ii] = (short)f2bf(f);
                    }
                }
                *(short8*)(As + row * 128 + ((k16 ^ (row & 7)) << 4)) = v;
            }
        }
        __syncthreads();
#pragma unroll
        for (int kk = 0; kk < 2; ++kk) {
            const int kg = kk * 4 + (lane >> 4);
            short8 af[4];
#pragma unroll
            for (int nr = 0; nr < 4; ++nr) {
                int row = wr * 64 + nr * 16 + (lane & 15);
                af[nr] = *(const short8*)(As + row * 128 + ((kg ^ (row & 7)) << 4));
            }
#pragma unroll
            for (int hf = 0; hf < 2; ++hf) {
                const char* Bs = hf ? Bs1 : Bs0;
                short8 bfr[4];
#pragma unroll
                for (int mc = 0; mc < 4; ++mc) {
                    int row = wc * 64 + mc * 16 + (lane & 15);
                    bfr[mc] = *(const short8*)(Bs + row * 128 + ((kg ^ (row & 7)) << 4));
                }
#pragma unroll
                for (int mc = 0; mc < 4; ++mc)
#pragma unroll
                    for (int nr = 0; nr < 4; ++nr)
                        acc[hf][mc][nr] = __builtin_amdgcn_mfma_f32_16x16x32_bf16(
                            bfr[mc], af[nr], acc[hf][mc][nr], 0, 0, 0);
            }
        }
        __syncthreads();
    }

    float* eL = (float*)smem;
    const int wrow = wr * 16 + (lane & 15);
    const int qc = (lane >> 4) << 2;

#pragma unroll
    for (int hf = 0; hf < 2; ++hf) {
        unsigned short* outp = hf ? tpreb : supb;
        for (int nr = 0; nr < 4; ++nr) {
            __syncthreads();
#pragma unroll
            for (int mc = 0; mc < 4; ++mc) {
                const int col = wc * 64 + mc * 16 + qc;
                f32x4 v = acc[hf][mc][nr];
                if (hf) v += *(const f32x4*)(bias + col);
                const int c16 = col >> 2;
                *(f32x4*)(eL + wrow * 256 + ((c16 ^ wrow) << 2)) = v;
            }
            __syncthreads();
            const int tr = tid >> 4, j = tid & 15;
            const int gr = r0 + (tr >> 4) * 64 + nr * 16 + (tr & 15);
            if (gr < kN) {
#pragma unroll
                for (int p = 0; p < 2; ++p) {
                    const int u = j + 16 * p;
                    f32x4 lo = *(const f32x4*)(eL + tr * 256 + (((2 * u) ^ tr) << 2));
                    f32x4 hi = *(const f32x4*)(eL + tr * 256 + (((2 * u + 1) ^ tr) << 2));
                    uint4 pk;
                    pk.x = (unsigned)f2bf(lo[0]) | ((unsigned)f2bf(lo[1]) << 16);
                    pk.y = (unsigned)f2bf(lo[2]) | ((unsigned)f2bf(lo[3]) << 16);
                    pk.z = (unsigned)f2bf(hi[0]) | ((unsigned)f2bf(hi[1]) << 16);
                    pk.w = (unsigned)f2bf(hi[2]) | ((unsigned)f2bf(hi[3]) << 16);
                    *(uint4*)(outp + (long)gr * 256 + u * 8) = pk;
                }
            }
        }
    }
}

// ---------------------------------------------------------------------------
// Block-layer fused GEMM (R11 version): y = [act | xagg](Mx512) @ Bt^T + bias.
// Tile 128x128, 4 waves (2x2), grid 782, XCD-chunked swizzle.
// ---------------------------------------------------------------------------
template<int RES>
__global__ __launch_bounds__(256) void gemm_blk(
    const unsigned short* __restrict__ act, const unsigned short* __restrict__ xagg,
    const unsigned short* __restrict__ Bt, const float* __restrict__ bias,
    const unsigned short* __restrict__ hbf_res,
    unsigned short* __restrict__ outbf, float* __restrict__ hf32)
{
    __shared__ __align__(16) char smem[32768];
    char* As = smem;             // 128 rows x 128 B
    char* Bs = smem + 16384;     // 128 out-cols x 128 B

    const int tid = threadIdx.x;
    const int wid = tid >> 6;      // 0..3
    const int lane = tid & 63;
    const int wr = wid >> 1, wc = wid & 1;

    const int nwg = gridDim.x;
    const int q = nwg >> 3, r = nwg & 7;
    const int xcd = blockIdx.x & 7, idx = blockIdx.x >> 3;
    const int t = (xcd < r ? xcd * (q + 1) : r * (q + 1) + (xcd - r) * q) + idx;
    const int r0 = (t >> 1) * 128;
    const int c0 = (t & 1) * 128;

    f32x4 acc[4][4];
#pragma unroll
    for (int i = 0; i < 4; ++i)
#pragma unroll
        for (int j = 0; j < 4; ++j) acc[i][j] = f32x4{0.f, 0.f, 0.f, 0.f};

    const int l_row = lane >> 3;
    const int l_c   = lane & 7;

    for (int k0 = 0; k0 < 512; k0 += 64) {
#pragma unroll
        for (int p = 0; p < 4; ++p) {
            int row = wid * 32 + p * 8 + l_row;
            int csw = l_c ^ (row & 7);
            const unsigned short* g = Bt + (long)(c0 + row) * 512 + k0 + csw * 8;
            gload_lds16(g, Bs + (wid * 32 + p * 8) * 128);
        }
        const unsigned short* Asrc = (k0 < 256) ? (act + k0) : (xagg + (k0 - 256));
#pragma unroll
        for (int p = 0; p < 4; ++p) {
            int row = wid * 32 + p * 8 + l_row;
            int grow = r0 + row; if (grow >= kN) grow = kN - 1;
            int csw = l_c ^ (row & 7);
            const unsigned short* g = Asrc + (long)grow * 256 + csw * 8;
            gload_lds16(g, As + (wid * 32 + p * 8) * 128);
        }
        __syncthreads();
#pragma unroll
        for (int kk = 0; kk < 2; ++kk) {
            short8 af[4], bfr[4];
            const int kg = kk * 4 + (lane >> 4);
#pragma unroll
            for (int nr = 0; nr < 4; ++nr) {
                int row = wr * 64 + nr * 16 + (lane & 15);
                af[nr] = *(const short8*)(As + row * 128 + ((kg ^ (row & 7)) << 4));
            }
#pragma unroll
            for (int mc = 0; mc < 4; ++mc) {
                int row = wc * 64 + mc * 16 + (lane & 15);
                bfr[mc] = *(const short8*)(Bs + row * 128 + ((kg ^ (row & 7)) << 4));
            }
#pragma unroll
            for (int mc = 0; mc < 4; ++mc)
#pragma unroll
                for (int nr = 0; nr < 4; ++nr)
                    acc[mc][nr] = __builtin_amdgcn_mfma_f32_16x16x32_bf16(
                        bfr[mc], af[nr], acc[mc][nr], 0, 0, 0);
        }
        __syncthreads();
    }

    float* eL = (float*)smem;                 // 32 x 128 fp32 = 16 KB
    const int wrow = wr * 16 + (lane & 15);   // 0..31
    const int qc = (lane >> 4) << 2;

    for (int nr = 0; nr < 4; ++nr) {
        __syncthreads();
#pragma unroll
        for (int mc = 0; mc < 4; ++mc) {
            const int col = wc * 64 + mc * 16 + qc;   // 0..127
            f32x4 v = acc[mc][nr] + *(const f32x4*)(bias + c0 + col);
            const int c16 = col >> 2;                 // 0..31
            *(f32x4*)(eL + wrow * 128 + ((c16 ^ wrow) << 2)) = v;
        }
        __syncthreads();
        const int tr = tid >> 3, j = tid & 7;         // 32 rows x 8 threads
        const int gr = r0 + (tr >> 4) * 64 + nr * 16 + (tr & 15);
        if (gr < kN) {
#pragma unroll
            for (int p = 0; p < 2; ++p) {
                const int u = j + 8 * p;              // 16B bf16 unit, 0..15
                f32x4 lo = *(const f32x4*)(eL + tr * 128 + (((2 * u) ^ tr) << 2));
                f32x4 hi = *(const f32x4*)(eL + tr * 128 + (((2 * u + 1) ^ tr) << 2));
#pragma unroll
                for (int ii = 0; ii < 4; ++ii) {
                    lo[ii] = fmaxf(lo[ii], 0.f);
                    hi[ii] = fmaxf(hi[ii], 0.f);
                }
                const long gcol = (long)gr * 256 + c0 + u * 8;
                if (RES >= 1) {
                    uint4 hv = *(const uint4*)(hbf_res + gcol);
                    lo[0] = (bf2f((unsigned short)(hv.x & 0xFFFF)) + lo[0]) * 0.5f;
                    lo[1] = (bf2f((unsigned short)(hv.x >> 16))    + lo[1]) * 0.5f;
                    lo[2] = (bf2f((unsigned short)(hv.y & 0xFFFF)) + lo[2]) * 0.5f;
                    lo[3] = (bf2f((unsigned short)(hv.y >> 16))    + lo[3]) * 0.5f;
                    hi[0] = (bf2f((unsigned short)(hv.z & 0xFFFF)) + hi[0]) * 0.5f;
                    hi[1] = (bf2f((unsigned short)(hv.z >> 16))    + hi[1]) * 0.5f;
                    hi[2] = (bf2f((unsigned short)(hv.w & 0xFFFF)) + hi[2]) * 0.5f;
                    hi[3] = (bf2f((unsigned short)(hv.w >> 16))    + hi[3]) * 0.5f;
                }
                if (RES == 2) {
                    *(f32x4*)(hf32 + gcol)     = lo;
                    *(f32x4*)(hf32 + gcol + 4) = hi;
                }
                uint4 pk;
                pk.x = (unsigned)f2bf(lo[0]) | ((unsigned)f2bf(lo[1]) << 16);
                pk.y = (unsigned)f2bf(lo[2]) | ((unsigned)f2bf(lo[3]) << 16);
                pk.z = (unsigned)f2bf(hi[0]) | ((unsigned)f2bf(hi[1]) << 16);
                pk.w = (unsigned)f2bf(hi[2]) | ((unsigned)f2bf(hi[3]) << 16);
                *(uint4*)(outbf + gcol) = pk;
            }
        }
    }
}

// ---------------------------------------------------------------------------
// CSR gather, 16 lanes/node: lane owns 16 bf16 cols (2 x uint4 per edge);
// 4-edge unroll -> 8 loads in flight per lane, 4 nodes per wave.
// MODE 0: xagg = bf16(sum ew*act[src])
// MODE 1: hbf  = bf16(relu(tpreb + sum ew*supb[src]))   (layer 1)
// ---------------------------------------------------------------------------
template<int MODE>
__global__ __launch_bounds__(256) void agg16_kernel(
    const unsigned short* __restrict__ srcbuf, const unsigned short* __restrict__ tpreb,
    const int* __restrict__ rowptr, const int* __restrict__ e_src,
    const float* __restrict__ e_w, unsigned short* __restrict__ outb)
{
    const int tid = threadIdx.x;
    const int sub = tid >> 4;          // 0..15 node slot
    const int l   = tid & 15;
    const long node = (long)blockIdx.x * 16 + sub;
    if (node >= kN) return;
    const int c0 = l * 16;             // 16 cols = 32 B

    f32x4 a0 = {0.f,0.f,0.f,0.f}, a1 = {0.f,0.f,0.f,0.f};
    f32x4 a2 = {0.f,0.f,0.f,0.f}, a3 = {0.f,0.f,0.f,0.f};

#define UNPK(A0, A1, V, W) \
    A0[0] += (W) * bf2f((unsigned short)((V).x & 0xFFFF)); \
    A0[1] += (W) * bf2f((unsigned short)((V).x >> 16));    \
    A0[2] += (W) * bf2f((unsigned short)((V).y & 0xFFFF)); \
    A0[3] += (W) * bf2f((unsigned short)((V).y >> 16));    \
    A1[0] += (W) * bf2f((unsigned short)((V).z & 0xFFFF)); \
    A1[1] += (W) * bf2f((unsigned short)((V).z >> 16));    \
    A1[2] += (W) * bf2f((unsigned short)((V).w & 0xFFFF)); \
    A1[3] += (W) * bf2f((unsigned short)((V).w >> 16));

    if (MODE == 1) {
        uint4 t0 = *(const uint4*)(tpreb + node * 256 + c0);
        uint4 t1 = *(const uint4*)(tpreb + node * 256 + c0 + 8);
        UNPK(a0, a1, t0, 1.f)
        UNPK(a2, a3, t1, 1.f)
    }

    int b = rowptr[node];
    const int e = rowptr[node + 1];

    for (; b + 4 <= e; b += 4) {
        const int s0 = e_src[b],     s1 = e_src[b + 1];
        const int s2 = e_src[b + 2], s3 = e_src[b + 3];
        const float w0 = e_w[b],     w1 = e_w[b + 1];
        const float w2 = e_w[b + 2], w3 = e_w[b + 3];
        const unsigned short* p0 = srcbuf + (long)s0 * 256 + c0;
        const unsigned short* p1 = srcbuf + (long)s1 * 256 + c0;
        const unsigned short* p2 = srcbuf + (long)s2 * 256 + c0;
        const unsigned short* p3 = srcbuf + (long)s3 * 256 + c0;
        uint4 va0 = *(const uint4*)(p0),     vb0 = *(const uint4*)(p0 + 8);
        uint4 va1 = *(const uint4*)(p1),     vb1 = *(const uint4*)(p1 + 8);
        uint4 va2 = *(const uint4*)(p2),     vb2 = *(const uint4*)(p2 + 8);
        uint4 va3 = *(const uint4*)(p3),     vb3 = *(const uint4*)(p3 + 8);
        UNPK(a0, a1, va0, w0) UNPK(a2, a3, vb0, w0)
        UNPK(a0, a1, va1, w1) UNPK(a2, a3, vb1, w1)
        UNPK(a0, a1, va2, w2) UNPK(a2, a3, vb2, w2)
        UNPK(a0, a1, va3, w3) UNPK(a2, a3, vb3, w3)
    }
    for (; b < e; ++b) {
        const int s = e_src[b];
        const float w = e_w[b];
        const unsigned short* p = srcbuf + (long)s * 256 + c0;
        uint4 va = *(const uint4*)(p);
        uint4 vb = *(const uint4*)(p + 8);
        UNPK(a0, a1, va, w) UNPK(a2, a3, vb, w)
    }
#undef UNPK

    if (MODE == 1) {
#pragma unroll
        for (int ii = 0; ii < 4; ++ii) {
            a0[ii] = fmaxf(a0[ii], 0.f); a1[ii] = fmaxf(a1[ii], 0.f);
            a2[ii] = fmaxf(a2[ii], 0.f); a3[ii] = fmaxf(a3[ii], 0.f);
        }
    }
    uint4 pk0, pk1;
    pk0.x = (unsigned)f2bf(a0[0]) | ((unsigned)f2bf(a0[1]) << 16);
    pk0.y = (unsigned)f2bf(a0[2]) | ((unsigned)f2bf(a0[3]) << 16);
    pk0.z = (unsigned)f2bf(a1[0]) | ((unsigned)f2bf(a1[1]) << 16);
    pk0.w = (unsigned)f2bf(a1[2]) | ((unsigned)f2bf(a1[3]) << 16);
    pk1.x = (unsigned)f2bf(a2[0]) | ((unsigned)f2bf(a2[1]) << 16);
    pk1.y = (unsigned)f2bf(a2[2]) | ((unsigned)f2bf(a2[3]) << 16);
    pk1.z = (unsigned)f2bf(a3[0]) | ((unsigned)f2bf(a3[1]) << 16);
    pk1.w = (unsigned)f2bf(a3[2]) | ((unsigned)f2bf(a3[3]) << 16);
    *(uint4*)(outb + node * 256 + c0)     = pk0;
    *(uint4*)(outb + node * 256 + c0 + 8) = pk1;
}

// ---------------------------------------------------------------------------
// Weight conversion
// ---------------------------------------------------------------------------
__global__ __launch_bounds__(256) void cvt_w1_kernel(
    const float* __restrict__ W1, const float* __restrict__ Wl1,
    unsigned short* __restrict__ out)
{
    int idx = blockIdx.x * 256 + threadIdx.x;       // 512*1024
    if (idx >= 512 * 1024) return;
    int c = idx >> 10, k = idx & 1023;
    float v = 0.f;
    if (k < kDIN) v = (c < 256) ? W1[(long)k * 256 + c] : Wl1[(long)k * 256 + (c - 256)];
    out[idx] = f2bf(v);
}

// blkc layout: [l][out-col c][k] ; k<256 -> Wl[k][c], k>=256 -> W[k-256][c]
__global__ __launch_bounds__(256) void cvt_blk_kernel(
    const float* __restrict__ blkW, const float* __restrict__ blkWl,
    unsigned short* __restrict__ out)
{
    int idx = blockIdx.x * 256 + threadIdx.x;       // 12*256*512
    if (idx >= 12 * 256 * 512) return;
    int l = idx >> 17;
    int rem = idx & 131071;
    int c = rem >> 9, k = rem & 511;
    float v = (k < 256) ? blkWl[((long)l * 256 + k) * 256 + c]
                        : blkW[((long)l * 256 + (k - 256)) * 256 + c];
    out[idx] = f2bf(v);
}

// ---------------------------------------------------------------------------
// CSR build: histogram -> hierarchical exclusive scan -> fill
// ---------------------------------------------------------------------------
__global__ __launch_bounds__(256) void hist_kernel(const int* __restrict__ dst,
                                                   int* __restrict__ counts)
{
    int e = blockIdx.x * 256 + threadIdx.x;
    if (e < kE) atomicAdd(&counts[dst[e]], 1);
}

__global__ __launch_bounds__(1024) void scan1_kernel(
    const int* __restrict__ counts, int* __restrict__ rowptr, int* __restrict__ bsum)
{
    __shared__ int s[1024];
    const int tid = threadIdx.x;
    const int g = blockIdx.x * 1024 + tid;
    const int v = (g < kN) ? counts[g] : 0;
    s[tid] = v; __syncthreads();
    for (int off = 1; off < 1024; off <<= 1) {
        int tv = (tid >= off) ? s[tid - off] : 0;
        __syncthreads();
        s[tid] += tv;
        __syncthreads();
    }
    if (g < kN) rowptr[g] = s[tid] - v;
    if (tid == 1023) bsum[blockIdx.x] = s[1023];
}

__global__ __launch_bounds__(64) void scan2_kernel(int* __restrict__ bsum, int nb)
{
    __shared__ int s[64];
    const int tid = threadIdx.x;
    const int v = (tid < nb) ? bsum[tid] : 0;
    s[tid] = v; __syncthreads();
    for (int off = 1; off < 64; off <<= 1) {
        int tv = (tid >= off) ? s[tid - off] : 0;
        __syncthreads();
        s[tid] += tv;
        __syncthreads();
    }
    if (tid < nb) bsum[tid] = s[tid] - v;
}

__global__ __launch_bounds__(256) void scan3_kernel(
    int* __restrict__ rowptr, const int* __restrict__ bsum, int* __restrict__ cursor)
{
    int g = blockIdx.x * 256 + threadIdx.x;
    if (g < kN) {
        int r = rowptr[g] + bsum[g >> 10];
        rowptr[g] = r;
        cursor[g] = r;
    }
    if (g == 0) rowptr[kN] = kE;
}

__global__ __launch_bounds__(256) void fill_kernel(
    const int* __restrict__ src, const int* __restrict__ dst,
    const float* __restrict__ ew, int* __restrict__ cursor,
    int* __restrict__ e_src, float* __restrict__ e_w)
{
    int e = blockIdx.x * 256 + threadIdx.x;
    if (e >= kE) return;
    int d = dst[e];
    int pos = atomicAdd(&cursor[d], 1);
    e_src[pos] = src[e];
    e_w[pos] = ew[e];
}

// ---------------------------------------------------------------------------
// Final layer (DOUT=3): one wave per row, reads bf16 hidden
// ---------------------------------------------------------------------------
__global__ __launch_bounds__(64) void final_layer_kernel(
    const unsigned short* __restrict__ hbf, const float* __restrict__ W2,
    const float* __restrict__ Wl2, const float* __restrict__ b2,
    float* __restrict__ sup2, float* __restrict__ x_out)
{
    const int row = blockIdx.x;
    const int lane = threadIdx.x;
    const unsigned short* hr = hbf + (long)row * kH;
    float accW[3] = {0.f, 0.f, 0.f};
    float accL[3] = {0.f, 0.f, 0.f};
#pragma unroll
    for (int kb = 0; kb < kH / 64; ++kb) {
        int k = kb * 64 + lane;
        float v = bf2f(hr[k]);
#pragma unroll
        for (int c = 0; c < 3; ++c) {
            accW[c] = fmaf(v, W2[k * 3 + c], accW[c]);
            accL[c] = fmaf(v, Wl2[k * 3 + c], accL[c]);
        }
    }
#pragma unroll
    for (int off = 32; off > 0; off >>= 1) {
#pragma unroll
        for (int c = 0; c < 3; ++c) {
            accW[c] += __shfl_down(accW[c], off);
            accL[c] += __shfl_down(accL[c], off);
        }
    }
    if (lane == 0) {
#pragma unroll
        for (int c = 0; c < 3; ++c) {
            sup2[row * 3 + c] = accW[c];
            x_out[row * 3 + c] = accL[c] + b2[c];
        }
    }
}

__global__ __launch_bounds__(256) void scatter3_kernel(
    const float* __restrict__ sup2, const int* __restrict__ src,
    const int* __restrict__ dst, const float* __restrict__ ew,
    float* __restrict__ x_out)
{
    int e = blockIdx.x * 256 + threadIdx.x;
    if (e >= kE) return;
    int s = src[e];
    int d = dst[e];
    float w = ew[e];
#pragma unroll
    for (int c = 0; c < 3; ++c)
        atomicAdd(&x_out[(long)d * 3 + c], w * sup2[(long)s * 3 + c]);
}

// ---------------------------------------------------------------------------
extern "C" void kernel_launch(void* const* d_in, const int* in_sizes, int n_in,
                              void* d_out, int out_size, void* d_ws, size_t ws_size,
                              hipStream_t stream)
{
    const float* x    = (const float*)d_in[0];
    const int*   src  = (const int*)d_in[1];
    const int*   dst  = (const int*)d_in[2];
    const float* ew   = (const float*)d_in[3];
    const float* W1   = (const float*)d_in[4];
    const float* Wl1  = (const float*)d_in[5];
    const float* b1   = (const float*)d_in[6];
    const float* blkW  = (const float*)d_in[7];
    const float* blkWl = (const float*)d_in[8];
    const float* blkb  = (const float*)d_in[9];
    const float* W2   = (const float*)d_in[10];
    const float* Wl2  = (const float*)d_in[11];
    const float* b2   = (const float*)d_in[12];

    float* out   = (float*)d_out;
    float* x_out = out;                       // N*3
    float* h     = out + (long)kN * 3;        // N*H fp32 = x_hidden output

    // ---- workspace carve-up
    char* w = (char*)d_ws;
    size_t off = 0;
    auto carve = [&](size_t bytes) { char* p = w + off; off = (off + bytes + 255) & ~(size_t)255; return p; };
    unsigned short* supb  = (unsigned short*)carve(12800000UL * 2);
    unsigned short* tpreb = (unsigned short*)carve(12800000UL * 2);  // layer-1 only
    unsigned short* tact  = (unsigned short*)carve(12800000UL * 2);
    unsigned short* hbf   = (unsigned short*)carve(12800000UL * 2);
    unsigned short* w1c   = (unsigned short*)carve(512UL * 1024 * 2);
    unsigned short* blkc  = (unsigned short*)carve(12UL * 256 * 512 * 2);
    int*   e_src  = (int*)carve(kE * 4);
    float* e_w    = (float*)carve(kE * 4);
    int*   counts = (int*)carve(50176 * 4);
    int*   rowptr = (int*)carve(50176 * 4);
    int*   cursor = (int*)carve(50176 * 4);
    int*   bsum   = (int*)carve(64 * 4);
    float* sup2   = (float*)carve((long)kN * 3 * 4);
    unsigned short* xagg = tpreb;             // alias: tpreb dead after agg_l1

    // optional bf16 copy of x (padded to stride 1024)
    const size_t xbf_bytes = (size_t)kN * 1024 * 2;
    unsigned short* xbf = nullptr;
    if (off + xbf_bytes + 256 <= ws_size)
        xbf = (unsigned short*)carve(xbf_bytes);

    // ---- CSR build
    hipMemsetAsync(counts, 0, 50176 * 4, stream);
    hist_kernel<<<(kE + 255) / 256, 256, 0, stream>>>(dst, counts);
    scan1_kernel<<<49, 1024, 0, stream>>>(counts, rowptr, bsum);
    scan2_kernel<<<1, 64, 0, stream>>>(bsum, 49);
    scan3_kernel<<<(kN + 255) / 256, 256, 0, stream>>>(rowptr, bsum, cursor);
    fill_kernel<<<(kE + 255) / 256, 256, 0, stream>>>(src, dst, ew, cursor, e_src, e_w);

    // ---- weight conversion
    cvt_w1_kernel<<<2048, 256, 0, stream>>>(W1, Wl1, w1c);
    cvt_blk_kernel<<<6144, 256, 0, stream>>>(blkW, blkWl, blkc);

    const int l1_grid  = 2 * ((kN + 127) / 128);   // 782 (2 col-tiles x 391)
    const int blk_grid = 2 * ((kN + 127) / 128);   // 782 (2 col-tiles of 128)
    const int agg_grid = (kN + 15) / 16;           // 3125 (16 nodes/block)

    // ---- Layer 1: hbf = bf16(relu(gconv(x)))
    if (xbf) {
        xcvt_kernel<<<kN, 128, 0, stream>>>(x, xbf);
        gemm_l1_bf<<<l1_grid, 512, 0, stream>>>(xbf, w1c, b1, supb, tpreb);
    } else {
        gemm_l1<<<(kN + 127) / 128, 512, 0, stream>>>(x, w1c, b1, supb, tpreb,
                                                      kN, 1024, kDIN, kDIN);
    }
    agg16_kernel<1><<<agg_grid, 256, 0, stream>>>(supb, tpreb, rowptr, e_src, e_w, hbf);

    // ---- 12 block convs (linearity order: agg-first, K=512 fused GEMM)
    for (int l = 0; l < 2 * kNBLK; ++l) {
        const unsigned short* act_in = (l & 1) ? tact : hbf;
        unsigned short* act_out      = (l & 1) ? hbf : tact;
        agg16_kernel<0><<<agg_grid, 256, 0, stream>>>(act_in, nullptr, rowptr, e_src, e_w, xagg);
        const unsigned short* B = blkc + (long)l * 256 * 512;
        const float* bb = blkb + (long)l * 256;
        if (l & 1) {
            if (l == 2 * kNBLK - 1)
                gemm_blk<2><<<blk_grid, 256, 0, stream>>>(act_in, xagg, B, bb, hbf, act_out, h);
            else
                gemm_blk<1><<<blk_grid, 256, 0, stream>>>(act_in, xagg, B, bb, hbf, act_out, nullptr);
        } else {
            gemm_blk<0><<<blk_grid, 256, 0, stream>>>(act_in, xagg, B, bb, nullptr, act_out, nullptr);
        }
    }

    // ---- final layer
    final_layer_kernel<<<kN, 64, 0, stream>>>(hbf, W2, Wl2, b2, sup2, x_out);
    scatter3_kernel<<<(kE + 255) / 256, 256, 0, stream>>>(sup2, src, dst, ew, x_out);
}

// Round 18
// 954.445 us; speedup vs baseline: 1.0796x; 1.0796x over previous
//
#include <hip/hip_runtime.h>

typedef __attribute__((ext_vector_type(8))) short short8;
typedef __attribute__((ext_vector_type(4))) float f32x4;
typedef __attribute__((ext_vector_type(4), aligned(4))) float f32x4u;  // 4B-aligned loads

constexpr int kN = 50000;
constexpr int kE = 300000;
constexpr int kDIN = 963;
constexpr int kH = 256;
constexpr int kNBLK = 6;

__device__ inline unsigned short f2bf(float f) {
    unsigned u = __float_as_uint(f);
    u = u + 0x7FFFu + ((u >> 16) & 1u);   // RTNE
    return (unsigned short)(u >> 16);
}
__device__ inline float bf2f(unsigned short s) {
    return __uint_as_float(((unsigned)s) << 16);
}

__device__ inline void gload_lds16(const void* g, void* l) {
    __builtin_amdgcn_global_load_lds(
        (const __attribute__((address_space(1))) void*)g,
        (__attribute__((address_space(3))) void*)l, 16, 0, 0);
}

// ---------------------------------------------------------------------------
// Layer-1 dual GEMM, single-pass: [supb | tpreb] = x @ [W1|Wl1]^T
// Tile 128 rows x 512 cols; fp32 A converted in-kernel (vectorized).
// 8 waves (2 row x 4 col); A staged once/K-step; two 32KB B buffers.
// Grid 391, XCD swizzle. (R13 best-measured configuration.)
// ---------------------------------------------------------------------------
__global__ __launch_bounds__(512) void gemm_l1(
    const float* __restrict__ Av, const unsigned short* __restrict__ Bt,
    const float* __restrict__ bias,
    unsigned short* __restrict__ supb, unsigned short* __restrict__ tpreb,
    int M, int Kpad, int Kvalid, int Astride)
{
    __shared__ __align__(16) char smem[81920];
    char* As  = smem;
    char* Bs0 = smem + 16384;
    char* Bs1 = smem + 49152;

    const int tid = threadIdx.x;
    const int wid = tid >> 6;
    const int lane = tid & 63;
    const int wr = wid >> 2, wc = wid & 3;

    const int nwg = gridDim.x;
    const int q = nwg >> 3, r = nwg & 7;
    const int xcd = blockIdx.x & 7, idx = blockIdx.x >> 3;
    const int t = (xcd < r ? xcd * (q + 1) : r * (q + 1) + (xcd - r) * q) + idx;
    const int r0 = t * 128;

    f32x4 acc[2][4][4];
#pragma unroll
    for (int hf = 0; hf < 2; ++hf)
#pragma unroll
        for (int i = 0; i < 4; ++i)
#pragma unroll
            for (int j = 0; j < 4; ++j) acc[hf][i][j] = f32x4{0.f, 0.f, 0.f, 0.f};

    const int l_row = lane >> 3;
    const int l_c   = lane & 7;

    for (int k0 = 0; k0 < Kpad; k0 += 64) {
#pragma unroll
        for (int p = 0; p < 4; ++p) {
            int row = wid * 32 + p * 8 + l_row;
            int csw = l_c ^ (row & 7);
            const unsigned short* g0 = Bt + (long)row * Kpad + k0 + csw * 8;
            gload_lds16(g0, Bs0 + (wid * 32 + p * 8) * 128);
            const unsigned short* g1 = Bt + (long)(256 + row) * Kpad + k0 + csw * 8;
            gload_lds16(g1, Bs1 + (wid * 32 + p * 8) * 128);
        }
        {
            const int row = tid >> 2;
            const int kq = tid & 3;
            int grow = r0 + row; if (grow >= M) grow = M - 1;
            const float* ar = Av + (long)grow * Astride;
#pragma unroll
            for (int j = 0; j < 2; ++j) {
                int k16 = kq * 2 + j;
                int kb = k0 + k16 * 8;
                short8 v;
                if (kb + 8 <= Kvalid) {
                    f32x4u f0 = *(const f32x4u*)(ar + kb);
                    f32x4u f1 = *(const f32x4u*)(ar + kb + 4);
#pragma unroll
                    for (int ii = 0; ii < 4; ++ii) {
                        v[ii]     = (short)f2bf(f0[ii]);
                        v[ii + 4] = (short)f2bf(f1[ii]);
                    }
                } else {
#pragma unroll
                    for (int ii = 0; ii < 8; ++ii) {
                        int k = kb + ii;
                        float f = (k < Kvalid) ? ar[k] : 0.f;
                        v[ii] = (short)f2bf(f);
                    }
                }
                *(short8*)(As + row * 128 + ((k16 ^ (row & 7)) << 4)) = v;
            }
        }
        __syncthreads();
#pragma unroll
        for (int kk = 0; kk < 2; ++kk) {
            const int kg = kk * 4 + (lane >> 4);
            short8 af[4];
#pragma unroll
            for (int nr = 0; nr < 4; ++nr) {
                int row = wr * 64 + nr * 16 + (lane & 15);
                af[nr] = *(const short8*)(As + row * 128 + ((kg ^ (row & 7)) << 4));
            }
#pragma unroll
            for (int hf = 0; hf < 2; ++hf) {
                const char* Bs = hf ? Bs1 : Bs0;
                short8 bfr[4];
#pragma unroll
                for (int mc = 0; mc < 4; ++mc) {
                    int row = wc * 64 + mc * 16 + (lane & 15);
                    bfr[mc] = *(const short8*)(Bs + row * 128 + ((kg ^ (row & 7)) << 4));
                }
#pragma unroll
                for (int mc = 0; mc < 4; ++mc)
#pragma unroll
                    for (int nr = 0; nr < 4; ++nr)
                        acc[hf][mc][nr] = __builtin_amdgcn_mfma_f32_16x16x32_bf16(
                            bfr[mc], af[nr], acc[hf][mc][nr], 0, 0, 0);
            }
        }
        __syncthreads();
    }

    float* eL = (float*)smem;
    const int wrow = wr * 16 + (lane & 15);
    const int qc = (lane >> 4) << 2;

#pragma unroll
    for (int hf = 0; hf < 2; ++hf) {
        unsigned short* outp = hf ? tpreb : supb;
        for (int nr = 0; nr < 4; ++nr) {
            __syncthreads();
#pragma unroll
            for (int mc = 0; mc < 4; ++mc) {
                const int col = wc * 64 + mc * 16 + qc;
                f32x4 v = acc[hf][mc][nr];
                if (hf) v += *(const f32x4*)(bias + col);
                const int c16 = col >> 2;
                *(f32x4*)(eL + wrow * 256 + ((c16 ^ wrow) << 2)) = v;
            }
            __syncthreads();
            const int tr = tid >> 4, j = tid & 15;
            const int gr = r0 + (tr >> 4) * 64 + nr * 16 + (tr & 15);
            if (gr < M) {
#pragma unroll
                for (int p = 0; p < 2; ++p) {
                    const int u = j + 16 * p;
                    f32x4 lo = *(const f32x4*)(eL + tr * 256 + (((2 * u) ^ tr) << 2));
                    f32x4 hi = *(const f32x4*)(eL + tr * 256 + (((2 * u + 1) ^ tr) << 2));
                    uint4 pk;
                    pk.x = (unsigned)f2bf(lo[0]) | ((unsigned)f2bf(lo[1]) << 16);
                    pk.y = (unsigned)f2bf(lo[2]) | ((unsigned)f2bf(lo[3]) << 16);
                    pk.z = (unsigned)f2bf(hi[0]) | ((unsigned)f2bf(hi[1]) << 16);
                    pk.w = (unsigned)f2bf(hi[2]) | ((unsigned)f2bf(hi[3]) << 16);
                    *(uint4*)(outp + (long)gr * 256 + u * 8) = pk;
                }
            }
        }
    }
}

// ---------------------------------------------------------------------------
// Block-layer fused GEMM: y = [act | xagg](Mx512) @ Bt^T + bias.
// Tile 128x128, 4 waves (2x2), grid 782, XCD-chunked swizzle.
// ---------------------------------------------------------------------------
template<int RES>
__global__ __launch_bounds__(256) void gemm_blk(
    const unsigned short* __restrict__ act, const unsigned short* __restrict__ xagg,
    const unsigned short* __restrict__ Bt, const float* __restrict__ bias,
    const unsigned short* __restrict__ hbf_res,
    unsigned short* __restrict__ outbf, float* __restrict__ hf32)
{
    __shared__ __align__(16) char smem[32768];
    char* As = smem;             // 128 rows x 128 B
    char* Bs = smem + 16384;     // 128 out-cols x 128 B

    const int tid = threadIdx.x;
    const int wid = tid >> 6;      // 0..3
    const int lane = tid & 63;
    const int wr = wid >> 1, wc = wid & 1;

    const int nwg = gridDim.x;
    const int q = nwg >> 3, r = nwg & 7;
    const int xcd = blockIdx.x & 7, idx = blockIdx.x >> 3;
    const int t = (xcd < r ? xcd * (q + 1) : r * (q + 1) + (xcd - r) * q) + idx;
    const int r0 = (t >> 1) * 128;
    const int c0 = (t & 1) * 128;

    f32x4 acc[4][4];
#pragma unroll
    for (int i = 0; i < 4; ++i)
#pragma unroll
        for (int j = 0; j < 4; ++j) acc[i][j] = f32x4{0.f, 0.f, 0.f, 0.f};

    const int l_row = lane >> 3;
    const int l_c   = lane & 7;

    for (int k0 = 0; k0 < 512; k0 += 64) {
#pragma unroll
        for (int p = 0; p < 4; ++p) {
            int row = wid * 32 + p * 8 + l_row;
            int csw = l_c ^ (row & 7);
            const unsigned short* g = Bt + (long)(c0 + row) * 512 + k0 + csw * 8;
            gload_lds16(g, Bs + (wid * 32 + p * 8) * 128);
        }
        const unsigned short* Asrc = (k0 < 256) ? (act + k0) : (xagg + (k0 - 256));
#pragma unroll
        for (int p = 0; p < 4; ++p) {
            int row = wid * 32 + p * 8 + l_row;
            int grow = r0 + row; if (grow >= kN) grow = kN - 1;
            int csw = l_c ^ (row & 7);
            const unsigned short* g = Asrc + (long)grow * 256 + csw * 8;
            gload_lds16(g, As + (wid * 32 + p * 8) * 128);
        }
        __syncthreads();
#pragma unroll
        for (int kk = 0; kk < 2; ++kk) {
            short8 af[4], bfr[4];
            const int kg = kk * 4 + (lane >> 4);
#pragma unroll
            for (int nr = 0; nr < 4; ++nr) {
                int row = wr * 64 + nr * 16 + (lane & 15);
                af[nr] = *(const short8*)(As + row * 128 + ((kg ^ (row & 7)) << 4));
            }
#pragma unroll
            for (int mc = 0; mc < 4; ++mc) {
                int row = wc * 64 + mc * 16 + (lane & 15);
                bfr[mc] = *(const short8*)(Bs + row * 128 + ((kg ^ (row & 7)) << 4));
            }
#pragma unroll
            for (int mc = 0; mc < 4; ++mc)
#pragma unroll
                for (int nr = 0; nr < 4; ++nr)
                    acc[mc][nr] = __builtin_amdgcn_mfma_f32_16x16x32_bf16(
                        bfr[mc], af[nr], acc[mc][nr], 0, 0, 0);
        }
        __syncthreads();
    }

    float* eL = (float*)smem;                 // 32 x 128 fp32 = 16 KB
    const int wrow = wr * 16 + (lane & 15);   // 0..31
    const int qc = (lane >> 4) << 2;

    for (int nr = 0; nr < 4; ++nr) {
        __syncthreads();
#pragma unroll
        for (int mc = 0; mc < 4; ++mc) {
            const int col = wc * 64 + mc * 16 + qc;   // 0..127
            f32x4 v = acc[mc][nr] + *(const f32x4*)(bias + c0 + col);
            const int c16 = col >> 2;                 // 0..31
            *(f32x4*)(eL + wrow * 128 + ((c16 ^ wrow) << 2)) = v;
        }
        __syncthreads();
        const int tr = tid >> 3, j = tid & 7;         // 32 rows x 8 threads
        const int gr = r0 + (tr >> 4) * 64 + nr * 16 + (tr & 15);
        if (gr < kN) {
#pragma unroll
            for (int p = 0; p < 2; ++p) {
                const int u = j + 8 * p;              // 16B bf16 unit, 0..15
                f32x4 lo = *(const f32x4*)(eL + tr * 128 + (((2 * u) ^ tr) << 2));
                f32x4 hi = *(const f32x4*)(eL + tr * 128 + (((2 * u + 1) ^ tr) << 2));
#pragma unroll
                for (int ii = 0; ii < 4; ++ii) {
                    lo[ii] = fmaxf(lo[ii], 0.f);
                    hi[ii] = fmaxf(hi[ii], 0.f);
                }
                const long gcol = (long)gr * 256 + c0 + u * 8;
                if (RES >= 1) {
                    uint4 hv = *(const uint4*)(hbf_res + gcol);
                    lo[0] = (bf2f((unsigned short)(hv.x & 0xFFFF)) + lo[0]) * 0.5f;
                    lo[1] = (bf2f((unsigned short)(hv.x >> 16))    + lo[1]) * 0.5f;
                    lo[2] = (bf2f((unsigned short)(hv.y & 0xFFFF)) + lo[2]) * 0.5f;
                    lo[3] = (bf2f((unsigned short)(hv.y >> 16))    + lo[3]) * 0.5f;
                    hi[0] = (bf2f((unsigned short)(hv.z & 0xFFFF)) + hi[0]) * 0.5f;
                    hi[1] = (bf2f((unsigned short)(hv.z >> 16))    + hi[1]) * 0.5f;
                    hi[2] = (bf2f((unsigned short)(hv.w & 0xFFFF)) + hi[2]) * 0.5f;
                    hi[3] = (bf2f((unsigned short)(hv.w >> 16))    + hi[3]) * 0.5f;
                }
                if (RES == 2) {
                    *(f32x4*)(hf32 + gcol)     = lo;
                    *(f32x4*)(hf32 + gcol + 4) = hi;
                }
                uint4 pk;
                pk.x = (unsigned)f2bf(lo[0]) | ((unsigned)f2bf(lo[1]) << 16);
                pk.y = (unsigned)f2bf(lo[2]) | ((unsigned)f2bf(lo[3]) << 16);
                pk.z = (unsigned)f2bf(hi[0]) | ((unsigned)f2bf(hi[1]) << 16);
                pk.w = (unsigned)f2bf(hi[2]) | ((unsigned)f2bf(hi[3]) << 16);
                *(uint4*)(outbf + gcol) = pk;
            }
        }
    }
}

// ---------------------------------------------------------------------------
// CSR gather, 16B-lane: one 32-lane half-wave per node, lane owns 8 bf16
// cols (uint4 loads), 4-edge unroll.
// MODE 0: xagg = bf16(sum ew*act[src])
// MODE 1: hbf  = bf16(relu(tpreb + sum ew*supb[src]))   (layer 1)
// ---------------------------------------------------------------------------
template<int MODE>
__global__ __launch_bounds__(256) void agg16_kernel(
    const unsigned short* __restrict__ srcbuf, const unsigned short* __restrict__ tpreb,
    const int* __restrict__ rowptr, const int* __restrict__ e_src,
    const float* __restrict__ e_w, unsigned short* __restrict__ outb)
{
    const int tid = threadIdx.x;
    const int sub = tid >> 5;          // 0..7 half-wave in block
    const int l   = tid & 31;
    const long node = (long)blockIdx.x * 8 + sub;
    if (node >= kN) return;
    const int c0 = l * 8;              // 8 cols = 16 B

    f32x4 a0 = {0.f, 0.f, 0.f, 0.f}, a1 = {0.f, 0.f, 0.f, 0.f};
    if (MODE == 1) {
        uint4 tv = *(const uint4*)(tpreb + node * 256 + c0);
        a0[0] = bf2f((unsigned short)(tv.x & 0xFFFF)); a0[1] = bf2f((unsigned short)(tv.x >> 16));
        a0[2] = bf2f((unsigned short)(tv.y & 0xFFFF)); a0[3] = bf2f((unsigned short)(tv.y >> 16));
        a1[0] = bf2f((unsigned short)(tv.z & 0xFFFF)); a1[1] = bf2f((unsigned short)(tv.z >> 16));
        a1[2] = bf2f((unsigned short)(tv.w & 0xFFFF)); a1[3] = bf2f((unsigned short)(tv.w >> 16));
    }

    int b = rowptr[node];
    const int e = rowptr[node + 1];

#define ACC16(V, W) \
    a0[0] += (W) * bf2f((unsigned short)((V).x & 0xFFFF)); \
    a0[1] += (W) * bf2f((unsigned short)((V).x >> 16));    \
    a0[2] += (W) * bf2f((unsigned short)((V).y & 0xFFFF)); \
    a0[3] += (W) * bf2f((unsigned short)((V).y >> 16));    \
    a1[0] += (W) * bf2f((unsigned short)((V).z & 0xFFFF)); \
    a1[1] += (W) * bf2f((unsigned short)((V).z >> 16));    \
    a1[2] += (W) * bf2f((unsigned short)((V).w & 0xFFFF)); \
    a1[3] += (W) * bf2f((unsigned short)((V).w >> 16));

    for (; b + 4 <= e; b += 4) {
        const int s0 = e_src[b],     s1 = e_src[b + 1];
        const int s2 = e_src[b + 2], s3 = e_src[b + 3];
        const float w0 = e_w[b],     w1 = e_w[b + 1];
        const float w2 = e_w[b + 2], w3 = e_w[b + 3];
        uint4 v0 = *(const uint4*)(srcbuf + (long)s0 * 256 + c0);
        uint4 v1 = *(const uint4*)(srcbuf + (long)s1 * 256 + c0);
        uint4 v2 = *(const uint4*)(srcbuf + (long)s2 * 256 + c0);
        uint4 v3 = *(const uint4*)(srcbuf + (long)s3 * 256 + c0);
        ACC16(v0, w0) ACC16(v1, w1) ACC16(v2, w2) ACC16(v3, w3)
    }
    for (; b < e; ++b) {
        const int s = e_src[b];
        const float w = e_w[b];
        uint4 v = *(const uint4*)(srcbuf + (long)s * 256 + c0);
        ACC16(v, w)
    }
#undef ACC16

    if (MODE == 1) {
#pragma unroll
        for (int ii = 0; ii < 4; ++ii) {
            a0[ii] = fmaxf(a0[ii], 0.f);
            a1[ii] = fmaxf(a1[ii], 0.f);
        }
    }
    uint4 pk;
    pk.x = (unsigned)f2bf(a0[0]) | ((unsigned)f2bf(a0[1]) << 16);
    pk.y = (unsigned)f2bf(a0[2]) | ((unsigned)f2bf(a0[3]) << 16);
    pk.z = (unsigned)f2bf(a1[0]) | ((unsigned)f2bf(a1[1]) << 16);
    pk.w = (unsigned)f2bf(a1[2]) | ((unsigned)f2bf(a1[3]) << 16);
    *(uint4*)(outb + node * 256 + c0) = pk;
}

// ---------------------------------------------------------------------------
// Weight conversion
// ---------------------------------------------------------------------------
__global__ __launch_bounds__(256) void cvt_w1_kernel(
    const float* __restrict__ W1, const float* __restrict__ Wl1,
    unsigned short* __restrict__ out)
{
    int idx = blockIdx.x * 256 + threadIdx.x;       // 512*1024
    if (idx >= 512 * 1024) return;
    int c = idx >> 10, k = idx & 1023;
    float v = 0.f;
    if (k < kDIN) v = (c < 256) ? W1[(long)k * 256 + c] : Wl1[(long)k * 256 + (c - 256)];
    out[idx] = f2bf(v);
}

// blkc layout: [l][out-col c][k] ; k<256 -> Wl[k][c], k>=256 -> W[k-256][c]
__global__ __launch_bounds__(256) void cvt_blk_kernel(
    const float* __restrict__ blkW, const float* __restrict__ blkWl,
    unsigned short* __restrict__ out)
{
    int idx = blockIdx.x * 256 + threadIdx.x;       // 12*256*512
    if (idx >= 12 * 256 * 512) return;
    int l = idx >> 17;
    int rem = idx & 131071;
    int c = rem >> 9, k = rem & 511;
    float v = (k < 256) ? blkWl[((long)l * 256 + k) * 256 + c]
                        : blkW[((long)l * 256 + (k - 256)) * 256 + c];
    out[idx] = f2bf(v);
}

// ---------------------------------------------------------------------------
// CSR build: histogram -> hierarchical exclusive scan -> fill
// ---------------------------------------------------------------------------
__global__ __launch_bounds__(256) void hist_kernel(const int* __restrict__ dst,
                                                   int* __restrict__ counts)
{
    int e = blockIdx.x * 256 + threadIdx.x;
    if (e < kE) atomicAdd(&counts[dst[e]], 1);
}

__global__ __launch_bounds__(1024) void scan1_kernel(
    const int* __restrict__ counts, int* __restrict__ rowptr, int* __restrict__ bsum)
{
    __shared__ int s[1024];
    const int tid = threadIdx.x;
    const int g = blockIdx.x * 1024 + tid;
    const int v = (g < kN) ? counts[g] : 0;
    s[tid] = v; __syncthreads();
    for (int off = 1; off < 1024; off <<= 1) {
        int tv = (tid >= off) ? s[tid - off] : 0;
        __syncthreads();
        s[tid] += tv;
        __syncthreads();
    }
    if (g < kN) rowptr[g] = s[tid] - v;
    if (tid == 1023) bsum[blockIdx.x] = s[1023];
}

__global__ __launch_bounds__(64) void scan2_kernel(int* __restrict__ bsum, int nb)
{
    __shared__ int s[64];
    const int tid = threadIdx.x;
    const int v = (tid < nb) ? bsum[tid] : 0;
    s[tid] = v; __syncthreads();
    for (int off = 1; off < 64; off <<= 1) {
        int tv = (tid >= off) ? s[tid - off] : 0;
        __syncthreads();
        s[tid] += tv;
        __syncthreads();
    }
    if (tid < nb) bsum[tid] = s[tid] - v;
}

__global__ __launch_bounds__(256) void scan3_kernel(
    int* __restrict__ rowptr, const int* __restrict__ bsum, int* __restrict__ cursor)
{
    int g = blockIdx.x * 256 + threadIdx.x;
    if (g < kN) {
        int r = rowptr[g] + bsum[g >> 10];
        rowptr[g] = r;
        cursor[g] = r;
    }
    if (g == 0) rowptr[kN] = kE;
}

__global__ __launch_bounds__(256) void fill_kernel(
    const int* __restrict__ src, const int* __restrict__ dst,
    const float* __restrict__ ew, int* __restrict__ cursor,
    int* __restrict__ e_src, float* __restrict__ e_w)
{
    int e = blockIdx.x * 256 + threadIdx.x;
    if (e >= kE) return;
    int d = dst[e];
    int pos = atomicAdd(&cursor[d], 1);
    e_src[pos] = src[e];
    e_w[pos] = ew[e];
}

// ---------------------------------------------------------------------------
// Final layer (DOUT=3): one wave per row, reads bf16 hidden
// ---------------------------------------------------------------------------
__global__ __launch_bounds__(64) void final_layer_kernel(
    const unsigned short* __restrict__ hbf, const float* __restrict__ W2,
    const float* __restrict__ Wl2, const float* __restrict__ b2,
    float* __restrict__ sup2, float* __restrict__ x_out)
{
    const int row = blockIdx.x;
    const int lane = threadIdx.x;
    const unsigned short* hr = hbf + (long)row * kH;
    float accW[3] = {0.f, 0.f, 0.f};
    float accL[3] = {0.f, 0.f, 0.f};
#pragma unroll
    for (int kb = 0; kb < kH / 64; ++kb) {
        int k = kb * 64 + lane;
        float v = bf2f(hr[k]);
#pragma unroll
        for (int c = 0; c < 3; ++c) {
            accW[c] = fmaf(v, W2[k * 3 + c], accW[c]);
            accL[c] = fmaf(v, Wl2[k * 3 + c], accL[c]);
        }
    }
#pragma unroll
    for (int off = 32; off > 0; off >>= 1) {
#pragma unroll
        for (int c = 0; c < 3; ++c) {
            accW[c] += __shfl_down(accW[c], off);
            accL[c] += __shfl_down(accL[c], off);
        }
    }
    if (lane == 0) {
#pragma unroll
        for (int c = 0; c < 3; ++c) {
            sup2[row * 3 + c] = accW[c];
            x_out[row * 3 + c] = accL[c] + b2[c];
        }
    }
}

__global__ __launch_bounds__(256) void scatter3_kernel(
    const float* __restrict__ sup2, const int* __restrict__ src,
    const int* __restrict__ dst, const float* __restrict__ ew,
    float* __restrict__ x_out)
{
    int e = blockIdx.x * 256 + threadIdx.x;
    if (e >= kE) return;
    int s = src[e];
    int d = dst[e];
    float w = ew[e];
#pragma unroll
    for (int c = 0; c < 3; ++c)
        atomicAdd(&x_out[(long)d * 3 + c], w * sup2[(long)s * 3 + c]);
}

// ---------------------------------------------------------------------------
extern "C" void kernel_launch(void* const* d_in, const int* in_sizes, int n_in,
                              void* d_out, int out_size, void* d_ws, size_t ws_size,
                              hipStream_t stream)
{
    const float* x    = (const float*)d_in[0];
    const int*   src  = (const int*)d_in[1];
    const int*   dst  = (const int*)d_in[2];
    const float* ew   = (const float*)d_in[3];
    const float* W1   = (const float*)d_in[4];
    const float* Wl1  = (const float*)d_in[5];
    const float* b1   = (const float*)d_in[6];
    const float* blkW  = (const float*)d_in[7];
    const float* blkWl = (const float*)d_in[8];
    const float* blkb  = (const float*)d_in[9];
    const float* W2   = (const float*)d_in[10];
    const float* Wl2  = (const float*)d_in[11];
    const float* b2   = (const float*)d_in[12];

    float* out   = (float*)d_out;
    float* x_out = out;                       // N*3
    float* h     = out + (long)kN * 3;        // N*H fp32 = x_hidden output

    // ---- workspace carve-up
    char* w = (char*)d_ws;
    size_t off = 0;
    auto carve = [&](size_t bytes) { char* p = w + off; off = (off + bytes + 255) & ~(size_t)255; return p; };
    unsigned short* supb  = (unsigned short*)carve(12800000UL * 2);
    unsigned short* tpreb = (unsigned short*)carve(12800000UL * 2);  // layer-1 only
    unsigned short* tact  = (unsigned short*)carve(12800000UL * 2);
    unsigned short* hbf   = (unsigned short*)carve(12800000UL * 2);
    unsigned short* w1c   = (unsigned short*)carve(512UL * 1024 * 2);
    unsigned short* blkc  = (unsigned short*)carve(12UL * 256 * 512 * 2);
    int*   e_src  = (int*)carve(kE * 4);
    float* e_w    = (float*)carve(kE * 4);
    int*   counts = (int*)carve(50176 * 4);
    int*   rowptr = (int*)carve(50176 * 4);
    int*   cursor = (int*)carve(50176 * 4);
    int*   bsum   = (int*)carve(64 * 4);
    float* sup2   = (float*)carve((long)kN * 3 * 4);
    unsigned short* xagg = tpreb;             // alias: tpreb dead after agg_l1

    // ---- CSR build
    hipMemsetAsync(counts, 0, 50176 * 4, stream);
    hist_kernel<<<(kE + 255) / 256, 256, 0, stream>>>(dst, counts);
    scan1_kernel<<<49, 1024, 0, stream>>>(counts, rowptr, bsum);
    scan2_kernel<<<1, 64, 0, stream>>>(bsum, 49);
    scan3_kernel<<<(kN + 255) / 256, 256, 0, stream>>>(rowptr, bsum, cursor);
    fill_kernel<<<(kE + 255) / 256, 256, 0, stream>>>(src, dst, ew, cursor, e_src, e_w);

    // ---- weight conversion
    cvt_w1_kernel<<<2048, 256, 0, stream>>>(W1, Wl1, w1c);
    cvt_blk_kernel<<<6144, 256, 0, stream>>>(blkW, blkWl, blkc);

    const int l1_grid  = (kN + 127) / 128;         // 391 (both col-halves/block)
    const int blk_grid = 2 * ((kN + 127) / 128);   // 782 (2 col-tiles of 128)
    const int agg_grid = (kN + 7) / 8;             // 6250 (8 nodes/block)

    // ---- Layer 1: hbf = bf16(relu(gconv(x)))
    gemm_l1<<<l1_grid, 512, 0, stream>>>(x, w1c, b1, supb, tpreb,
                                         kN, 1024, kDIN, kDIN);
    agg16_kernel<1><<<agg_grid, 256, 0, stream>>>(supb, tpreb, rowptr, e_src, e_w, hbf);

    // ---- 12 block convs (linearity order: agg-first, K=512 fused GEMM)
    for (int l = 0; l < 2 * kNBLK; ++l) {
        const unsigned short* act_in = (l & 1) ? tact : hbf;
        unsigned short* act_out      = (l & 1) ? hbf : tact;
        agg16_kernel<0><<<agg_grid, 256, 0, stream>>>(act_in, nullptr, rowptr, e_src, e_w, xagg);
        const unsigned short* B = blkc + (long)l * 256 * 512;
        const float* bb = blkb + (long)l * 256;
        if (l & 1) {
            if (l == 2 * kNBLK - 1)
                gemm_blk<2><<<blk_grid, 256, 0, stream>>>(act_in, xagg, B, bb, hbf, act_out, h);
            else
                gemm_blk<1><<<blk_grid, 256, 0, stream>>>(act_in, xagg, B, bb, hbf, act_out, nullptr);
        } else {
            gemm_blk<0><<<blk_grid, 256, 0, stream>>>(act_in, xagg, B, bb, nullptr, act_out, nullptr);
        }
    }

    // ---- final layer
    final_layer_kernel<<<kN, 64, 0, stream>>>(hbf, W2, Wl2, b2, sup2, x_out);
    scatter3_kernel<<<(kE + 255) / 256, 256, 0, stream>>>(sup2, src, dst, ew, x_out);
}